// Round 11
// baseline (869.655 us; speedup 1.0000x reference)
//
#include <hip/hip_runtime.h>

#define ALPHA 0.2f
#define NN 8192
#define FIN 128
#define FOUT 64
#define NS 32
#define JS 256
#define K0_ITER 4   // diagnostic: idempotent repeats to surface k0 in rocprof top-5
#define K2_ITER 24  // diagnostic: accumulator-scaling repeats (cancels in k3's o/L)

typedef short bf16x8 __attribute__((ext_vector_type(8)));
typedef float f32x4 __attribute__((ext_vector_type(4)));

// K0: compress adj -> bitmasks (PROVEN R5-R8 layout).
// adjb[row][grp][c] (c=0..3), bit l of word c = adj[row][grp*256 + 4*l + c].
__global__ __launch_bounds__(256) void gat_k0(const int* __restrict__ adj,
                                              unsigned long long* __restrict__ adjb,
                                              int iter) {
    int t = threadIdx.x, w = t >> 6, l = t & 63;
    int row = blockIdx.x * 4 + w;
    const int4* a4 = (const int4*)(adj + (size_t)row * NN);
    unsigned long long* ob = adjb + (size_t)row * 32 * 4;
    for (int rep = 0; rep < iter; ++rep) {
#pragma unroll 4
        for (int it = 0; it < 32; ++it) {
            int4 av = a4[it * 64 + l];
            unsigned long long b0 = __ballot(av.x != 0);
            unsigned long long b1 = __ballot(av.y != 0);
            unsigned long long b2 = __ballot(av.z != 0);
            unsigned long long b3 = __ballot(av.w != 0);
            if (l == 0) {
                ulonglong4 v;
                v.x = b0; v.y = b1; v.z = b2; v.w = b3;
                *(ulonglong4*)(ob + it * 4) = v;
            }
        }
    }
}

// K1: Wh = h @ W; epilogue writes exp-factor tables for the separable LeakyReLU-exp:
// srcE[i]=exp(src_i), srcE[NN+i]=exp(a*src_i); dstF[j]=exp(dst_j), dstF[NN+j]=exp(a*dst_j).
__global__ __launch_bounds__(256) void gat_k1(const float* __restrict__ h,
                                              const float* __restrict__ W,
                                              const float* __restrict__ a,
                                              float* __restrict__ Wh,
                                              float* __restrict__ srcE,
                                              float* __restrict__ dstF) {
    __shared__ float wlds[FIN * FOUT];  // 32 KB
    int t = threadIdx.x;
    const float4* W4 = (const float4*)W;
    float4* wlds4 = (float4*)wlds;
#pragma unroll
    for (int q = 0; q < 8; ++q) wlds4[q * 256 + t] = W4[q * 256 + t];
    __syncthreads();
    int wave = t >> 6, lane = t & 63;
    int row = blockIdx.x * 4 + wave;
    const float4* h4 = (const float4*)(h + (size_t)row * FIN);
    float acc = 0.f;
#pragma unroll
    for (int k4 = 0; k4 < 32; ++k4) {
        float4 hv = h4[k4];
        acc = fmaf(hv.x, wlds[(k4 * 4 + 0) * 64 + lane], acc);
        acc = fmaf(hv.y, wlds[(k4 * 4 + 1) * 64 + lane], acc);
        acc = fmaf(hv.z, wlds[(k4 * 4 + 2) * 64 + lane], acc);
        acc = fmaf(hv.w, wlds[(k4 * 4 + 3) * 64 + lane], acc);
    }
    Wh[(size_t)row * 64 + lane] = acc;
    float sa = acc * a[lane];
    float da = acc * a[64 + lane];
#pragma unroll
    for (int off = 32; off; off >>= 1) {
        sa += __shfl_xor(sa, off);
        da += __shfl_xor(da, off);
    }
    if (lane == 0) {
        srcE[row] = __expf(sa);
        srcE[NN + row] = __expf(ALPHA * sa);
        dstF[row] = __expf(da);
        dstF[NN + row] = __expf(ALPHA * da);
    }
}

// K1b: build MFMA-ready B fragments (unchanged, proven).
// whbt2[tile t][frag q][lane l] (uint4 = 8 bf16): elem e = bf16(Wh[32t + 8*(l>>4) + e][16q + (l&15)]).
__global__ __launch_bounds__(256) void gat_k1b(const float* __restrict__ Wh,
                                               uint4* __restrict__ whbt2) {
    __shared__ float wt[32 * 64];  // 8 KB
    int tid = threadIdx.x;
    int t = blockIdx.x;
    const float4* s4 = (const float4*)(Wh + (size_t)t * 2048);
    float4* l4 = (float4*)wt;
    l4[tid] = s4[tid];
    l4[tid + 256] = s4[tid + 256];
    __syncthreads();
    int q = tid >> 6, l = tid & 63, r = l & 15, g = l >> 4;
    unsigned pk[4];
#pragma unroll
    for (int k = 0; k < 4; ++k) {
        float lo = wt[(8 * g + 2 * k + 0) * 64 + 16 * q + r];
        float hi = wt[(8 * g + 2 * k + 1) * 64 + 16 * q + r];
        asm("v_cvt_pk_bf16_f32 %0, %1, %2" : "=v"(pk[k]) : "v"(lo), "v"(hi));
    }
    whbt2[(size_t)t * 256 + tid] = make_uint4(pk[0], pk[1], pk[2], pk[3]);
}

// K2: fused mask + exp + PV via MFMA (R10 structure verbatim, separable-exp path).
// Runtime `iter` repeats the compute loop WITHOUT resetting accumulators: pl/pacc
// scale by iter, cancelling exactly in k3's o/L quotient (proven R8).
__global__ __launch_bounds__(256, 4) void gat_k2(const unsigned long long* __restrict__ adjb,
                                                 const uint4* __restrict__ whbt2,
                                                 const float* __restrict__ srcE,
                                                 const float* __restrict__ dstF,
                                                 float* __restrict__ pl,
                                                 float* __restrict__ pacc,
                                                 int iter) {
    __shared__ uint4 lds_b[8 * 256];      // 32 KB: 8 j-tiles x 256 frags
    __shared__ ulonglong2 lds_m[64 * 2];  // 2 KB: [row][half] mask words for this 256-j grp
    __shared__ float lds_f1[256];         // 1 KB: F1 slice
    __shared__ float lds_f2[256];         // 1 KB: F2 slice
    const int tid = threadIdx.x;
    const int l = tid & 63, w = tid >> 6;
    const int r = l & 15, g = l >> 4;
    const int s = blockIdx.x, rg = blockIdx.y;
    const int task = rg * NS + s;
    const int rowbase = rg * 64;
    const int rho = w * 16 + r;
    const int row = rowbase + rho;
    const int j0 = s * JS;

    // ---- stage (one barrier)
    const uint4* bsrc = whbt2 + (size_t)(j0 >> 5) * 256;
#pragma unroll
    for (int k = 0; k < 8; ++k) lds_b[k * 256 + tid] = bsrc[k * 256 + tid];
    if (tid < 128) {  // row = tid>>1, half = tid&1
        lds_m[tid] = ((const ulonglong2*)(adjb + (size_t)(rowbase + (tid >> 1)) * 128 + (size_t)s * 4))[tid & 1];
    }
    if (tid < 64) ((float4*)lds_f1)[tid] = ((const float4*)(dstF + j0))[tid];
    else if (tid < 128) ((float4*)lds_f2)[tid - 64] = ((const float4*)(dstF + NN + j0))[tid - 64];
    __syncthreads();

    const float E1 = srcE[row];
    const float E2 = srcE[NN + row];
    f32x4 acc0 = {0.f, 0.f, 0.f, 0.f}, acc1 = acc0, acc2 = acc0, acc3 = acc0, accl = acc0;
    bf16x8 bones;
#pragma unroll
    for (int e = 0; e < 8; ++e) bones[e] = (short)0x3F80;  // bf16 1.0

    const ulonglong2 mA = lds_m[rho * 2], mB = lds_m[rho * 2 + 1];
    const unsigned long long m0 = mA.x, m1 = mA.y, m2 = mB.x, m3 = mB.y;

    for (int rep = 0; rep < iter; ++rep) {
#pragma unroll 2
        for (int t = 0; t < 8; ++t) {
            float4 fa = *(const float4*)(lds_f1 + t * 32 + g * 8);
            float4 fb = *(const float4*)(lds_f1 + t * 32 + g * 8 + 4);
            float4 ga = *(const float4*)(lds_f2 + t * 32 + g * 8);
            float4 gb = *(const float4*)(lds_f2 + t * 32 + g * 8 + 4);
            const int hb = t * 8 + 2 * g;

            float f1s[8] = {fa.x, fa.y, fa.z, fa.w, fb.x, fb.y, fb.z, fb.w};
            float f2s[8] = {ga.x, ga.y, ga.z, ga.w, gb.x, gb.y, gb.z, gb.w};
            float p[8];
#pragma unroll
            for (int e = 0; e < 8; ++e) {
                float pe = fmaxf(E1 * f1s[e], E2 * f2s[e]);  // = exp(LeakyReLU(src_i + dst_j))
                unsigned long long mm = (e & 3) == 0 ? m0 : (e & 3) == 1 ? m1
                                      : (e & 3) == 2 ? m2 : m3;
                unsigned bit = (unsigned)(mm >> (hb + (e >> 2))) & 1u;
                p[e] = bit ? pe : 0.f;
            }
            unsigned pw0, pw1, pw2, pw3;
            asm("v_cvt_pk_bf16_f32 %0, %1, %2" : "=v"(pw0) : "v"(p[0]), "v"(p[1]));
            asm("v_cvt_pk_bf16_f32 %0, %1, %2" : "=v"(pw1) : "v"(p[2]), "v"(p[3]));
            asm("v_cvt_pk_bf16_f32 %0, %1, %2" : "=v"(pw2) : "v"(p[4]), "v"(p[5]));
            asm("v_cvt_pk_bf16_f32 %0, %1, %2" : "=v"(pw3) : "v"(p[6]), "v"(p[7]));
            bf16x8 af = __builtin_bit_cast(bf16x8, make_uint4(pw0, pw1, pw2, pw3));

            uint4 cb0 = lds_b[t * 256 + 0 * 64 + l];
            uint4 cb1 = lds_b[t * 256 + 1 * 64 + l];
            uint4 cb2 = lds_b[t * 256 + 2 * 64 + l];
            uint4 cb3 = lds_b[t * 256 + 3 * 64 + l];
            acc0 = __builtin_amdgcn_mfma_f32_16x16x32_bf16(af, __builtin_bit_cast(bf16x8, cb0), acc0, 0, 0, 0);
            acc1 = __builtin_amdgcn_mfma_f32_16x16x32_bf16(af, __builtin_bit_cast(bf16x8, cb1), acc1, 0, 0, 0);
            acc2 = __builtin_amdgcn_mfma_f32_16x16x32_bf16(af, __builtin_bit_cast(bf16x8, cb2), acc2, 0, 0, 0);
            acc3 = __builtin_amdgcn_mfma_f32_16x16x32_bf16(af, __builtin_bit_cast(bf16x8, cb3), acc3, 0, 0, 0);
            accl = __builtin_amdgcn_mfma_f32_16x16x32_bf16(af, bones, accl, 0, 0, 0);
        }
    }

    // accl: row m = g*4+reg, all 16 cols identical -> store from col lane r==0
    if (r == 0) {
        float* plo = pl + (size_t)task * 64 + w * 16 + g * 4;
        plo[0] = accl[0]; plo[1] = accl[1]; plo[2] = accl[2]; plo[3] = accl[3];
    }

    // C layout (verified): col = lane&15, row_m = (lane>>4)*4 + reg
    float* po = pacc + (size_t)task * 4096 + (size_t)(w * 16) * 64;
#pragma unroll
    for (int reg = 0; reg < 4; ++reg) {
        int m = g * 4 + reg;
        po[m * 64 + 0 * 16 + r] = acc0[reg];
        po[m * 64 + 1 * 16 + r] = acc1[reg];
        po[m * 64 + 2 * 16 + r] = acc2[reg];
        po[m * 64 + 3 * 16 + r] = acc3[reg];
    }
}

// K3: combine split partials + ELU. block=256 (4 waves), wave=row, lane=f.
__global__ __launch_bounds__(256) void gat_k3(const float* __restrict__ pl,
                                              const float* __restrict__ pacc,
                                              float* __restrict__ out) {
    int t = threadIdx.x;
    int wave = t >> 6, lane = t & 63;
    int row = blockIdx.x * 4 + wave;
    int rg = row >> 6, rr = row & 63;
    float L = 0.f, o = 0.f;
    for (int s2 = 0; s2 < NS; ++s2) {
        L += pl[(size_t)(rg * NS + s2) * 64 + rr];
        o += pacc[(size_t)(rg * NS + s2) * 4096 + rr * 64 + lane];
    }
    float hp = o / L;
    out[(size_t)row * 64 + lane] = hp > 0.f ? hp : __expf(hp) - 1.f;
}

extern "C" void kernel_launch(void* const* d_in, const int* in_sizes, int n_in,
                              void* d_out, int out_size, void* d_ws, size_t ws_size,
                              hipStream_t stream) {
    const float* h = (const float*)d_in[0];
    const int* adj = (const int*)d_in[1];
    const float* W = (const float*)d_in[2];
    const float* a = (const float*)d_in[3];
    float* out = (float*)d_out;
    float* ws = (float*)d_ws;

    // floats: Wh 524288 + srcE 16384 + dstF 16384 + pl 262144 + pacc 16777216
    //         + whbt2 262144 + adjb 2097152  ~= 80 MB (ws ~1 GiB)
    float* Wh = ws;
    float* srcE = Wh + (size_t)NN * FOUT;
    float* dstF = srcE + 2 * NN;
    float* pl = dstF + 2 * NN;
    float* pacc = pl + (size_t)128 * NS * 64;
    uint4* whbt2 = (uint4*)(pacc + (size_t)128 * NS * 4096);                  // 1 MB
    unsigned long long* adjb = (unsigned long long*)((float*)whbt2 + 262144); // 8 MB

    gat_k0<<<dim3(NN / 4), dim3(256), 0, stream>>>(adj, adjb, K0_ITER);
    gat_k1<<<dim3(NN / 4), dim3(256), 0, stream>>>(h, W, a, Wh, srcE, dstF);
    gat_k1b<<<dim3(NN / 32), dim3(256), 0, stream>>>(Wh, whbt2);
    gat_k2<<<dim3(NS, 128), dim3(256), 0, stream>>>(adjb, whbt2, srcE, dstF, pl, pacc, K2_ITER);
    gat_k3<<<dim3(NN / 4), dim3(256), 0, stream>>>(pl, pacc, out);
}

// Round 12
// 410.630 us; speedup vs baseline: 2.1179x; 2.1179x over previous
//
#include <hip/hip_runtime.h>

#define ALPHA 0.2f
#define NN 8192
#define FIN 128
#define FOUT 64
#define NS 8        // j-split tasks per row-group; each task = 4 x 256-j slices
#define K3_ITER 12  // diagnostic: idempotent repeats to surface k3 in rocprof top-5

typedef short bf16x8 __attribute__((ext_vector_type(8)));
typedef float f32x4 __attribute__((ext_vector_type(4)));

// K0: compress adj -> bitmasks (PROVEN layout).
// adjb[row][grp][c] (c=0..3), bit l of word c = adj[row][grp*256 + 4*l + c].
__global__ __launch_bounds__(256) void gat_k0(const int* __restrict__ adj,
                                              unsigned long long* __restrict__ adjb) {
    int t = threadIdx.x, w = t >> 6, l = t & 63;
    int row = blockIdx.x * 4 + w;
    const int4* a4 = (const int4*)(adj + (size_t)row * NN);
    unsigned long long* ob = adjb + (size_t)row * 32 * 4;
#pragma unroll 4
    for (int it = 0; it < 32; ++it) {
        int4 av = a4[it * 64 + l];
        unsigned long long b0 = __ballot(av.x != 0);
        unsigned long long b1 = __ballot(av.y != 0);
        unsigned long long b2 = __ballot(av.z != 0);
        unsigned long long b3 = __ballot(av.w != 0);
        if (l == 0) {
            ulonglong4 v;
            v.x = b0; v.y = b1; v.z = b2; v.w = b3;
            *(ulonglong4*)(ob + it * 4) = v;
        }
    }
}

// K1: Wh = h @ W; epilogue writes exp-factor tables for the separable LeakyReLU-exp.
__global__ __launch_bounds__(256) void gat_k1(const float* __restrict__ h,
                                              const float* __restrict__ W,
                                              const float* __restrict__ a,
                                              float* __restrict__ Wh,
                                              float* __restrict__ srcE,
                                              float* __restrict__ dstF) {
    __shared__ float wlds[FIN * FOUT];  // 32 KB
    int t = threadIdx.x;
    const float4* W4 = (const float4*)W;
    float4* wlds4 = (float4*)wlds;
#pragma unroll
    for (int q = 0; q < 8; ++q) wlds4[q * 256 + t] = W4[q * 256 + t];
    __syncthreads();
    int wave = t >> 6, lane = t & 63;
    int row = blockIdx.x * 4 + wave;
    const float4* h4 = (const float4*)(h + (size_t)row * FIN);
    float acc = 0.f;
#pragma unroll
    for (int k4 = 0; k4 < 32; ++k4) {
        float4 hv = h4[k4];
        acc = fmaf(hv.x, wlds[(k4 * 4 + 0) * 64 + lane], acc);
        acc = fmaf(hv.y, wlds[(k4 * 4 + 1) * 64 + lane], acc);
        acc = fmaf(hv.z, wlds[(k4 * 4 + 2) * 64 + lane], acc);
        acc = fmaf(hv.w, wlds[(k4 * 4 + 3) * 64 + lane], acc);
    }
    Wh[(size_t)row * 64 + lane] = acc;
    float sa = acc * a[lane];
    float da = acc * a[64 + lane];
#pragma unroll
    for (int off = 32; off; off >>= 1) {
        sa += __shfl_xor(sa, off);
        da += __shfl_xor(da, off);
    }
    if (lane == 0) {
        srcE[row] = __expf(sa);
        srcE[NN + row] = __expf(ALPHA * sa);
        dstF[row] = __expf(da);
        dstF[NN + row] = __expf(ALPHA * da);
    }
}

// K1b: build MFMA-ready B fragments (unchanged, proven).
__global__ __launch_bounds__(256) void gat_k1b(const float* __restrict__ Wh,
                                               uint4* __restrict__ whbt2) {
    __shared__ float wt[32 * 64];  // 8 KB
    int tid = threadIdx.x;
    int t = blockIdx.x;
    const float4* s4 = (const float4*)(Wh + (size_t)t * 2048);
    float4* l4 = (float4*)wt;
    l4[tid] = s4[tid];
    l4[tid + 256] = s4[tid + 256];
    __syncthreads();
    int q = tid >> 6, l = tid & 63, r = l & 15, g = l >> 4;
    unsigned pk[4];
#pragma unroll
    for (int k = 0; k < 4; ++k) {
        float lo = wt[(8 * g + 2 * k + 0) * 64 + 16 * q + r];
        float hi = wt[(8 * g + 2 * k + 1) * 64 + 16 * q + r];
        asm("v_cvt_pk_bf16_f32 %0, %1, %2" : "=v"(pk[k]) : "v"(lo), "v"(hi));
    }
    whbt2[(size_t)t * 256 + tid] = make_uint4(pk[0], pk[1], pk[2], pk[3]);
}

// K2: fused mask + exp + PV via MFMA (R10 inner loop verbatim). Each block now
// accumulates FOUR 256-j slices (double-barrier re-stage per slice, R7-proven
// sync pattern) before writing partials -> pacc shrinks 67->16.8 MB.
__global__ __launch_bounds__(256, 4) void gat_k2(const unsigned long long* __restrict__ adjb,
                                                 const uint4* __restrict__ whbt2,
                                                 const float* __restrict__ srcE,
                                                 const float* __restrict__ dstF,
                                                 float* __restrict__ pl,
                                                 float* __restrict__ pacc) {
    __shared__ uint4 lds_b[8 * 256];      // 32 KB: 8 j-tiles x 256 frags
    __shared__ ulonglong2 lds_m[64 * 2];  // 2 KB: masks for current 256-j slice
    __shared__ float lds_f1[256];         // 1 KB
    __shared__ float lds_f2[256];         // 1 KB
    const int tid = threadIdx.x;
    const int l = tid & 63, w = tid >> 6;
    const int r = l & 15, g = l >> 4;
    const int s = blockIdx.x, rg = blockIdx.y;
    const int task = rg * NS + s;
    const int rowbase = rg * 64;
    const int rho = w * 16 + r;
    const int row = rowbase + rho;

    const float E1 = srcE[row];
    const float E2 = srcE[NN + row];
    f32x4 acc0 = {0.f, 0.f, 0.f, 0.f}, acc1 = acc0, acc2 = acc0, acc3 = acc0, accl = acc0;
    bf16x8 bones;
#pragma unroll
    for (int e = 0; e < 8; ++e) bones[e] = (short)0x3F80;  // bf16 1.0

#pragma unroll 1
    for (int sl = 0; sl < 4; ++sl) {
        const int grp = s * 4 + sl;   // 256-j slice index
        const int j0 = grp * 256;
        if (sl) __syncthreads();      // all waves done reading previous slice's LDS
        const uint4* bsrc = whbt2 + (size_t)(j0 >> 5) * 256;
#pragma unroll
        for (int k = 0; k < 8; ++k) lds_b[k * 256 + tid] = bsrc[k * 256 + tid];
        if (tid < 128) {  // row = tid>>1, half = tid&1
            lds_m[tid] = ((const ulonglong2*)(adjb + (size_t)(rowbase + (tid >> 1)) * 128 + (size_t)grp * 4))[tid & 1];
        }
        if (tid < 64) ((float4*)lds_f1)[tid] = ((const float4*)(dstF + j0))[tid];
        else if (tid < 128) ((float4*)lds_f2)[tid - 64] = ((const float4*)(dstF + NN + j0))[tid - 64];
        __syncthreads();

        const ulonglong2 mA = lds_m[rho * 2], mB = lds_m[rho * 2 + 1];
        const unsigned long long m0 = mA.x, m1 = mA.y, m2 = mB.x, m3 = mB.y;

#pragma unroll 2
        for (int t = 0; t < 8; ++t) {
            float4 fa = *(const float4*)(lds_f1 + t * 32 + g * 8);
            float4 fb = *(const float4*)(lds_f1 + t * 32 + g * 8 + 4);
            float4 ga = *(const float4*)(lds_f2 + t * 32 + g * 8);
            float4 gb = *(const float4*)(lds_f2 + t * 32 + g * 8 + 4);
            const int hb = t * 8 + 2 * g;

            float f1s[8] = {fa.x, fa.y, fa.z, fa.w, fb.x, fb.y, fb.z, fb.w};
            float f2s[8] = {ga.x, ga.y, ga.z, ga.w, gb.x, gb.y, gb.z, gb.w};
            float p[8];
#pragma unroll
            for (int e = 0; e < 8; ++e) {
                float pe = fmaxf(E1 * f1s[e], E2 * f2s[e]);  // = exp(LeakyReLU(src_i + dst_j))
                unsigned long long mm = (e & 3) == 0 ? m0 : (e & 3) == 1 ? m1
                                      : (e & 3) == 2 ? m2 : m3;
                unsigned bit = (unsigned)(mm >> (hb + (e >> 2))) & 1u;
                p[e] = bit ? pe : 0.f;
            }
            unsigned pw0, pw1, pw2, pw3;
            asm("v_cvt_pk_bf16_f32 %0, %1, %2" : "=v"(pw0) : "v"(p[0]), "v"(p[1]));
            asm("v_cvt_pk_bf16_f32 %0, %1, %2" : "=v"(pw1) : "v"(p[2]), "v"(p[3]));
            asm("v_cvt_pk_bf16_f32 %0, %1, %2" : "=v"(pw2) : "v"(p[4]), "v"(p[5]));
            asm("v_cvt_pk_bf16_f32 %0, %1, %2" : "=v"(pw3) : "v"(p[6]), "v"(p[7]));
            bf16x8 af = __builtin_bit_cast(bf16x8, make_uint4(pw0, pw1, pw2, pw3));

            uint4 cb0 = lds_b[t * 256 + 0 * 64 + l];
            uint4 cb1 = lds_b[t * 256 + 1 * 64 + l];
            uint4 cb2 = lds_b[t * 256 + 2 * 64 + l];
            uint4 cb3 = lds_b[t * 256 + 3 * 64 + l];
            acc0 = __builtin_amdgcn_mfma_f32_16x16x32_bf16(af, __builtin_bit_cast(bf16x8, cb0), acc0, 0, 0, 0);
            acc1 = __builtin_amdgcn_mfma_f32_16x16x32_bf16(af, __builtin_bit_cast(bf16x8, cb1), acc1, 0, 0, 0);
            acc2 = __builtin_amdgcn_mfma_f32_16x16x32_bf16(af, __builtin_bit_cast(bf16x8, cb2), acc2, 0, 0, 0);
            acc3 = __builtin_amdgcn_mfma_f32_16x16x32_bf16(af, __builtin_bit_cast(bf16x8, cb3), acc3, 0, 0, 0);
            accl = __builtin_amdgcn_mfma_f32_16x16x32_bf16(af, bones, accl, 0, 0, 0);
        }
    }

    // accl: row m = g*4+reg, all 16 cols identical -> store from col lane r==0
    if (r == 0) {
        float* plo = pl + (size_t)task * 64 + w * 16 + g * 4;
        plo[0] = accl[0]; plo[1] = accl[1]; plo[2] = accl[2]; plo[3] = accl[3];
    }

    // C layout (verified): col = lane&15, row_m = (lane>>4)*4 + reg
    float* po = pacc + (size_t)task * 4096 + (size_t)(w * 16) * 64;
#pragma unroll
    for (int reg = 0; reg < 4; ++reg) {
        int m = g * 4 + reg;
        po[m * 64 + 0 * 16 + r] = acc0[reg];
        po[m * 64 + 1 * 16 + r] = acc1[reg];
        po[m * 64 + 2 * 16 + r] = acc2[reg];
        po[m * 64 + 3 * 16 + r] = acc3[reg];
    }
}

// K3: combine split partials + ELU. block=256 (4 waves), wave=row, lane=f.
// Fully unrolled NS=8 loop -> all loads issued up-front. Runtime iter (idempotent)
// is diagnostic only.
__global__ __launch_bounds__(256) void gat_k3(const float* __restrict__ pl,
                                              const float* __restrict__ pacc,
                                              float* __restrict__ out, int iter) {
    int t = threadIdx.x;
    int wave = t >> 6, lane = t & 63;
    int row = blockIdx.x * 4 + wave;
    int rg = row >> 6, rr = row & 63;
    for (int rep = 0; rep < iter; ++rep) {
        float L = 0.f, o = 0.f;
#pragma unroll
        for (int s2 = 0; s2 < NS; ++s2) {
            L += pl[(size_t)(rg * NS + s2) * 64 + rr];
            o += pacc[(size_t)(rg * NS + s2) * 4096 + rr * 64 + lane];
        }
        float hp = o / L;
        out[(size_t)row * 64 + lane] = hp > 0.f ? hp : __expf(hp) - 1.f;
    }
}

extern "C" void kernel_launch(void* const* d_in, const int* in_sizes, int n_in,
                              void* d_out, int out_size, void* d_ws, size_t ws_size,
                              hipStream_t stream) {
    const float* h = (const float*)d_in[0];
    const int* adj = (const int*)d_in[1];
    const float* W = (const float*)d_in[2];
    const float* a = (const float*)d_in[3];
    float* out = (float*)d_out;
    float* ws = (float*)d_ws;

    // floats: Wh 524288 + srcE 16384 + dstF 16384 + pl 65536 + pacc 4194304
    //         + whbt2 262144 + adjb 2097152  ~= 29 MB (ws ~1 GiB)
    float* Wh = ws;
    float* srcE = Wh + (size_t)NN * FOUT;
    float* dstF = srcE + 2 * NN;
    float* pl = dstF + 2 * NN;
    float* pacc = pl + (size_t)128 * NS * 64;
    uint4* whbt2 = (uint4*)(pacc + (size_t)128 * NS * 4096);                  // 1 MB
    unsigned long long* adjb = (unsigned long long*)((float*)whbt2 + 262144); // 8 MB

    gat_k0<<<dim3(NN / 4), dim3(256), 0, stream>>>(adj, adjb);
    gat_k1<<<dim3(NN / 4), dim3(256), 0, stream>>>(h, W, a, Wh, srcE, dstF);
    gat_k1b<<<dim3(NN / 32), dim3(256), 0, stream>>>(Wh, whbt2);
    gat_k2<<<dim3(NS, 128), dim3(256), 0, stream>>>(adjb, whbt2, srcE, dstF, pl, pacc);
    gat_k3<<<dim3(NN / 4), dim3(256), 0, stream>>>(pl, pacc, out, K3_ITER);
}